// Round 1
// baseline (2255.981 us; speedup 1.0000x reference)
//
#include <hip/hip_runtime.h>
#include <cstdint>
#include <cstddef>

// DeformConv2d: B=8, Cin=256, H=W=64, Cout=256, K=3, stride=1, pad=1, dil=1
// Fused kernel: bilinear im2col (LDS-staged, 16-channel chunks) + fp32 dot.
// Block = 256 threads (4 waves) handles (b, ho, co_half): 64 px × 128 co.
// wave w owns co range [co_half*128 + w*32, +32); lane = wo (px).

#define B_   8
#define C_   256
#define H_   64
#define W_   64
#define CO_  256
#define KK_  9
#define CK   16            // channels per LDS chunk
#define KSLAB (CK * KK_)   // 144

__global__ __launch_bounds__(256, 2) void dcn_fused(
    const float* __restrict__ x,
    const float* __restrict__ offset,
    const float* __restrict__ weight,
    const float* __restrict__ bias,
    float* __restrict__ out)
{
    __shared__ float4   t_w[KK_ * 64];     // 4 corner weights (0 if invalid)
    __shared__ uint32_t t_idx[KK_ * 64];   // packed clamped coords y0|x0|y1|x1
    __shared__ float    cols[KSLAB * 64];  // [k-within-chunk][px]

    const int bid  = blockIdx.x;           // 1024 = 2 * 64 * 8
    const int half = bid & 1;              // co half
    const int ho   = (bid >> 1) & 63;
    const int b    = bid >> 7;

    const int t    = threadIdx.x;
    const int lane = t & 63;               // px = wo
    const int wave = t >> 6;

    // ---- bilinear tables: one entry per (kk, wo) ----
    for (int e = t; e < KK_ * 64; e += 256) {
        const int kk = e >> 6;
        const int wo = e & 63;
        const int ky = kk / 3, kx = kk % 3;
        const float offy = offset[(((b * 18) + kk * 2 + 0) * 64 + ho) * 64 + wo];
        const float offx = offset[(((b * 18) + kk * 2 + 1) * 64 + ho) * 64 + wo];
        const float py  = (float)(ho - 1 + ky) + offy;
        const float pxx = (float)(wo - 1 + kx) + offx;
        const float y0f = floorf(py), x0f = floorf(pxx);
        const float wy = py - y0f, wx = pxx - x0f;
        const int y0 = (int)y0f, x0 = (int)x0f;
        const int y1 = y0 + 1,   x1 = x0 + 1;
        const float vy0 = (y0 >= 0 && y0 < H_) ? 1.f : 0.f;
        const float vy1 = (y1 >= 0 && y1 < H_) ? 1.f : 0.f;
        const float vx0 = (x0 >= 0 && x0 < W_) ? 1.f : 0.f;
        const float vx1 = (x1 >= 0 && x1 < W_) ? 1.f : 0.f;
        float4 wv;
        wv.x = (1.f - wy) * (1.f - wx) * vy0 * vx0;
        wv.y = (1.f - wy) * wx         * vy0 * vx1;
        wv.z = wy         * (1.f - wx) * vy1 * vx0;
        wv.w = wy         * wx         * vy1 * vx1;
        const int y0c = min(max(y0, 0), H_ - 1);
        const int x0c = min(max(x0, 0), W_ - 1);
        const int y1c = min(max(y1, 0), H_ - 1);
        const int x1c = min(max(x1, 0), W_ - 1);
        t_idx[e] = (uint32_t)y0c | ((uint32_t)x0c << 8) |
                   ((uint32_t)y1c << 16) | ((uint32_t)x1c << 24);
        t_w[e] = wv;
    }
    __syncthreads();

    float acc[32];
#pragma unroll
    for (int i = 0; i < 32; ++i) acc[i] = 0.f;

    const int co_base = __builtin_amdgcn_readfirstlane(half * 128 + wave * 32);

    for (int c0 = 0; c0 < C_; c0 += CK) {
        // ---- stage bilinear columns for this chunk: [144][64] ----
#pragma unroll 4
        for (int j = 0; j < KSLAB / 4; ++j) {        // 36 items/thread
            const int e       = wave + 4 * j;        // 0..143
            const int c_local = e / KK_;
            const int kk      = e % KK_;
            const uint32_t pidx = t_idx[kk * 64 + lane];
            const float4   wv   = t_w[kk * 64 + lane];
            const float* xb = x + (size_t)(b * C_ + c0 + c_local) * (H_ * W_);
            const int y0c =  pidx        & 255;
            const int x0c = (pidx >> 8)  & 255;
            const int y1c = (pidx >> 16) & 255;
            const int x1c = (pidx >> 24) & 255;
            const float v = wv.x * xb[y0c * W_ + x0c]
                          + wv.y * xb[y0c * W_ + x1c]
                          + wv.z * xb[y1c * W_ + x0c]
                          + wv.w * xb[y1c * W_ + x1c];
            cols[e * 64 + lane] = v;
        }
        __syncthreads();

        // ---- accumulate: 32 co × (144 k) ----
        const float* wbase = weight + (size_t)co_base * (C_ * KK_) + c0 * KK_;
        for (int g = 0; g < KSLAB / 8; ++g) {        // 18 groups of 8 k
            float v[8];
#pragma unroll
            for (int m = 0; m < 8; ++m) v[m] = cols[(g * 8 + m) * 64 + lane];
#pragma unroll
            for (int ci = 0; ci < 32; ++ci) {
                const float* wr = wbase + ci * (C_ * KK_) + g * 8;
                const float4 wa = *(const float4*)(wr);
                const float4 wb = *(const float4*)(wr + 4);
                acc[ci] += wa.x * v[0] + wa.y * v[1] + wa.z * v[2] + wa.w * v[3]
                         + wb.x * v[4] + wb.y * v[5] + wb.z * v[6] + wb.w * v[7];
            }
        }
        __syncthreads();
    }

    // ---- epilogue ----
#pragma unroll
    for (int ci = 0; ci < 32; ++ci) {
        const int co = co_base + ci;
        out[((size_t)(b * CO_ + co) * H_ + ho) * W_ + lane] = acc[ci] + bias[co];
    }
}

extern "C" void kernel_launch(void* const* d_in, const int* in_sizes, int n_in,
                              void* d_out, int out_size, void* d_ws, size_t ws_size,
                              hipStream_t stream) {
    const float* x      = (const float*)d_in[0];
    const float* offset = (const float*)d_in[1];
    const float* weight = (const float*)d_in[2];
    const float* bias   = (const float*)d_in[3];
    float* out = (float*)d_out;
    (void)in_sizes; (void)n_in; (void)out_size; (void)d_ws; (void)ws_size;

    dim3 grid(2 * 64 * B_);   // (co_half, ho, b) = 1024 blocks
    dim3 block(256);
    hipLaunchKernelGGL(dcn_fused, grid, block, 0, stream, x, offset, weight, bias, out);
}

// Round 2
// 505.465 us; speedup vs baseline: 4.4632x; 4.4632x over previous
//
#include <hip/hip_runtime.h>
#include <cstdint>
#include <cstddef>

// DeformConv2d B=8 C=256 H=W=64 Cout=256 K=3 s=1 p=1 d=1
// Fused: bilinear im2col (bf16, LDS-staged per 32-channel chunk) + MFMA GEMM.
// Grid = (b, ho) = 512 blocks. Block = 256 thr (4 waves).
// Block tile: 256co x 64px (px = wo). Wave w: co in [w*64, w*64+64).
// K ordering: k = c*9 + kk  (matches weight [co][c][kk] flat layout).

#define B_   8
#define C_   256
#define H_   64
#define W_   64
#define CO_  256
#define KK_  9
#define CC   32              // channels per chunk
#define KSLAB (CC * KK_)     // 288 k per chunk = 9 MFMA k-steps
#define PADK 296             // padded k row (bf16 elems): 592B rows, 16B aligned, /16 odd

typedef short  short8 __attribute__((ext_vector_type(8)));
typedef float  f32x4  __attribute__((ext_vector_type(4)));

__device__ inline short f2bf(float f) {   // fast round-to-nearest-even fp32->bf16
    uint32_t u = __builtin_bit_cast(uint32_t, f);
    u += 0x7FFFu + ((u >> 16) & 1u);
    return (short)(u >> 16);
}

__global__ __launch_bounds__(256, 3) void dcn_mfma(
    const float* __restrict__ x,
    const float* __restrict__ offset,
    const float* __restrict__ weight,
    const float* __restrict__ bias,
    float* __restrict__ out)
{
    __shared__ f32x4    t_w[KK_ * 64];      // 4 corner weights (0 if invalid)
    __shared__ uint32_t t_idx[KK_ * 64];    // packed clamped coords y0|x0|y1|x1
    __shared__ short    cols[64 * PADK];    // [px][k] bf16 columns for one chunk

    const int bid = blockIdx.x;             // 512 = 64 * 8
    const int ho  = bid & 63;
    const int b   = bid >> 6;

    const int t    = threadIdx.x;
    const int lane = t & 63;
    const int wave = t >> 6;

    // ---- bilinear tables: one entry per (kk, wo) ----
    for (int e = t; e < KK_ * 64; e += 256) {
        const int kk = e >> 6;
        const int wo = e & 63;
        const int ky = kk / 3, kx = kk % 3;
        const float offy = offset[(((b * 18) + kk * 2 + 0) * 64 + ho) * 64 + wo];
        const float offx = offset[(((b * 18) + kk * 2 + 1) * 64 + ho) * 64 + wo];
        const float py  = (float)(ho - 1 + ky) + offy;
        const float pxx = (float)(wo - 1 + kx) + offx;
        const float y0f = floorf(py), x0f = floorf(pxx);
        const float wy = py - y0f, wx = pxx - x0f;
        const int y0 = (int)y0f, x0 = (int)x0f;
        const int y1 = y0 + 1,   x1 = x0 + 1;
        const float vy0 = (y0 >= 0 && y0 < H_) ? 1.f : 0.f;
        const float vy1 = (y1 >= 0 && y1 < H_) ? 1.f : 0.f;
        const float vx0 = (x0 >= 0 && x0 < W_) ? 1.f : 0.f;
        const float vx1 = (x1 >= 0 && x1 < W_) ? 1.f : 0.f;
        f32x4 wv;
        wv[0] = (1.f - wy) * (1.f - wx) * vy0 * vx0;
        wv[1] = (1.f - wy) * wx         * vy0 * vx1;
        wv[2] = wy         * (1.f - wx) * vy1 * vx0;
        wv[3] = wy         * wx         * vy1 * vx1;
        const int y0c = min(max(y0, 0), H_ - 1);
        const int x0c = min(max(x0, 0), W_ - 1);
        const int y1c = min(max(y1, 0), H_ - 1);
        const int x1c = min(max(x1, 0), W_ - 1);
        t_idx[e] = (uint32_t)y0c | ((uint32_t)x0c << 8) |
                   ((uint32_t)y1c << 16) | ((uint32_t)x1c << 24);
        t_w[e] = wv;
    }
    __syncthreads();

    f32x4 acc[4][4];   // [mt][nt]
#pragma unroll
    for (int i = 0; i < 4; ++i)
#pragma unroll
        for (int j = 0; j < 4; ++j)
            acc[i][j] = (f32x4)0.f;

    const int co0 = __builtin_amdgcn_readfirstlane(wave * 64);
    const int m_l = lane & 15;        // m / n sub-index within fragment
    const int k_l = (lane >> 4) << 3; // k sub-offset (8 contiguous per lane)

    for (int c0 = 0; c0 < C_; c0 += CC) {
        // ---- stage bf16 columns for this chunk: cols[px][0..287] ----
        const int px = lane;
#pragma unroll
        for (int i = 0; i < 9; ++i) {
            const int o = wave + 4 * i;   // octet 0..35 (8 consecutive k each)
            short8 vs;
#pragma unroll
            for (int j = 0; j < 8; ++j) {
                const int k  = o * 8 + j;
                const int c  = k / 9;
                const int kk = k - c * 9;
                const uint32_t pidx = t_idx[kk * 64 + px];
                const f32x4    wv   = t_w[kk * 64 + px];
                const float* xb = x + ((size_t)(b * C_ + c0 + c) << 12);
                const int y0c =  pidx        & 255;
                const int x0c = (pidx >> 8)  & 255;
                const int y1c = (pidx >> 16) & 255;
                const int x1c = (pidx >> 24) & 255;
                const float v = wv[0] * xb[y0c * W_ + x0c]
                              + wv[1] * xb[y0c * W_ + x1c]
                              + wv[2] * xb[y1c * W_ + x0c]
                              + wv[3] * xb[y1c * W_ + x1c];
                vs[j] = f2bf(v);
            }
            *reinterpret_cast<short8*>(&cols[px * PADK + o * 8]) = vs;
        }
        __syncthreads();

        // ---- MFMA over 9 k-steps ----
#pragma unroll
        for (int s = 0; s < 9; ++s) {
            const int krow = s * 32 + k_l;
            short8 bf[4];
#pragma unroll
            for (int nt = 0; nt < 4; ++nt)
                bf[nt] = *reinterpret_cast<const short8*>(
                    &cols[(nt * 16 + m_l) * PADK + krow]);
            const int kglob = c0 * 9 + krow;
#pragma unroll
            for (int mt = 0; mt < 4; ++mt) {
                const float* wr = weight + (size_t)(co0 + mt * 16 + m_l) * (C_ * KK_) + kglob;
                const f32x4 wa = *reinterpret_cast<const f32x4*>(wr);
                const f32x4 wb = *reinterpret_cast<const f32x4*>(wr + 4);
                short8 af;
#pragma unroll
                for (int j = 0; j < 4; ++j) { af[j] = f2bf(wa[j]); af[j + 4] = f2bf(wb[j]); }
#pragma unroll
                for (int nt = 0; nt < 4; ++nt)
                    acc[mt][nt] = __builtin_amdgcn_mfma_f32_16x16x32_bf16(
                        af, bf[nt], acc[mt][nt], 0, 0, 0);
            }
        }
        __syncthreads();
    }

    // ---- epilogue: D mapping col=lane&15 (n=px), row=(lane>>4)*4+r (m=co) ----
    const int r0 = (lane >> 4) << 2;
#pragma unroll
    for (int mt = 0; mt < 4; ++mt) {
#pragma unroll
        for (int r = 0; r < 4; ++r) {
            const int co = co0 + mt * 16 + r0 + r;
            const float bv = bias[co];
            float* orow = out + ((size_t)(b * CO_ + co) * H_ + ho) * W_;
#pragma unroll
            for (int nt = 0; nt < 4; ++nt) {
                const int wo = nt * 16 + m_l;
                orow[wo] = acc[mt][nt][r] + bv;
            }
        }
    }
}

extern "C" void kernel_launch(void* const* d_in, const int* in_sizes, int n_in,
                              void* d_out, int out_size, void* d_ws, size_t ws_size,
                              hipStream_t stream) {
    const float* x      = (const float*)d_in[0];
    const float* offset = (const float*)d_in[1];
    const float* weight = (const float*)d_in[2];
    const float* bias   = (const float*)d_in[3];
    float* out = (float*)d_out;
    (void)in_sizes; (void)n_in; (void)out_size; (void)d_ws; (void)ws_size;

    dim3 grid(64 * B_);   // (ho, b) = 512 blocks
    dim3 block(256);
    hipLaunchKernelGGL(dcn_mfma, grid, block, 0, stream, x, offset, weight, bias, out);
}

// Round 3
// 347.792 us; speedup vs baseline: 6.4866x; 1.4534x over previous
//
#include <hip/hip_runtime.h>
#include <cstdint>
#include <cstddef>

// DeformConv2d B=8 C=256 H=W=64 Cout=256 K=3 s=1 p=1 d=1
// Prepass: weight fp32 -> bf16 into d_ws (1.18 MB, L2-resident).
// Main: fused bilinear im2col (bf16 LDS cols per 32-ch chunk) + MFMA GEMM.
// Grid = (b, ho) = 512 blocks x 512 thr (8 waves). Block tile 256co x 64px.
// Wave (wm,wn): wm in [0,4) -> 64-co group, wn in [0,2) -> 32-px group.
// K ordering: k = c*9 + kk (matches weight [co][c][kk] flat layout).

#define B_   8
#define C_   256
#define H_   64
#define W_   64
#define CO_  256
#define KK_  9
#define CC   32              // channels per chunk
#define KSLAB (CC * KK_)     // 288 k per chunk = 9 MFMA k-steps
#define PADK 296             // padded k row (bf16): 592B rows, 16B-aligned, /16 odd

typedef short  short4_t __attribute__((ext_vector_type(4)));
typedef short  short8   __attribute__((ext_vector_type(8)));
typedef float  f32x4    __attribute__((ext_vector_type(4)));

__device__ inline short f2bf(float f) {   // round-to-nearest-even fp32->bf16
    uint32_t u = __builtin_bit_cast(uint32_t, f);
    u += 0x7FFFu + ((u >> 16) & 1u);
    return (short)(u >> 16);
}

// ---- prepass: weight fp32 -> bf16 ----
__global__ __launch_bounds__(256) void w2bf(const float* __restrict__ w,
                                            short* __restrict__ wb, int n8) {
    const int i = blockIdx.x * 256 + threadIdx.x;
    if (i >= n8) return;
    const f32x4 a = *reinterpret_cast<const f32x4*>(w + i * 8);
    const f32x4 b = *reinterpret_cast<const f32x4*>(w + i * 8 + 4);
    short8 v;
#pragma unroll
    for (int j = 0; j < 4; ++j) { v[j] = f2bf(a[j]); v[j + 4] = f2bf(b[j]); }
    *reinterpret_cast<short8*>(wb + i * 8) = v;
}

__global__ __launch_bounds__(512, 4) void dcn_mfma(
    const float* __restrict__ x,
    const float* __restrict__ offset,
    const short* __restrict__ wbf,     // bf16 weight [256][2304]
    const float* __restrict__ bias,
    float* __restrict__ out)
{
    __shared__ f32x4    t_w[KK_ * 64];      // 4 corner weights (0 if invalid)
    __shared__ uint32_t t_idx[KK_ * 64];    // packed clamped coords
    __shared__ short    cols[64 * PADK];    // [px][k] bf16 columns, one chunk

    const int bid = blockIdx.x;             // 512 = 64 * 8
    const int ho  = bid & 63;
    const int b   = bid >> 6;

    const int t    = threadIdx.x;
    const int lane = t & 63;
    const int wave = t >> 6;

    // ---- bilinear tables: one entry per (kk, wo) ----
    for (int e = t; e < KK_ * 64; e += 512) {
        const int kk = e >> 6;
        const int wo = e & 63;
        const int ky = kk / 3, kx = kk % 3;
        const float offy = offset[(((b * 18) + kk * 2 + 0) * 64 + ho) * 64 + wo];
        const float offx = offset[(((b * 18) + kk * 2 + 1) * 64 + ho) * 64 + wo];
        const float py  = (float)(ho - 1 + ky) + offy;
        const float pxx = (float)(wo - 1 + kx) + offx;
        const float y0f = floorf(py), x0f = floorf(pxx);
        const float wy = py - y0f, wx = pxx - x0f;
        const int y0 = (int)y0f, x0 = (int)x0f;
        const int y1 = y0 + 1,   x1 = x0 + 1;
        const float vy0 = (y0 >= 0 && y0 < H_) ? 1.f : 0.f;
        const float vy1 = (y1 >= 0 && y1 < H_) ? 1.f : 0.f;
        const float vx0 = (x0 >= 0 && x0 < W_) ? 1.f : 0.f;
        const float vx1 = (x1 >= 0 && x1 < W_) ? 1.f : 0.f;
        f32x4 wv;
        wv[0] = (1.f - wy) * (1.f - wx) * vy0 * vx0;
        wv[1] = (1.f - wy) * wx         * vy0 * vx1;
        wv[2] = wy         * (1.f - wx) * vy1 * vx0;
        wv[3] = wy         * wx         * vy1 * vx1;
        const int y0c = min(max(y0, 0), H_ - 1);
        const int x0c = min(max(x0, 0), W_ - 1);
        const int y1c = min(max(y1, 0), H_ - 1);
        const int x1c = min(max(x1, 0), W_ - 1);
        t_idx[e] = (uint32_t)y0c | ((uint32_t)x0c << 8) |
                   ((uint32_t)y1c << 16) | ((uint32_t)x1c << 24);
        t_w[e] = wv;
    }
    __syncthreads();

    f32x4 acc[4][2];   // [mt co][nt px]
#pragma unroll
    for (int i = 0; i < 4; ++i) { acc[i][0] = (f32x4)0.f; acc[i][1] = (f32x4)0.f; }

    const int wm = wave >> 1;          // co-64 group
    const int wn = wave & 1;           // px-32 group
    const int co0 = __builtin_amdgcn_readfirstlane(wm * 64);
    const int px0 = __builtin_amdgcn_readfirstlane(wn * 32);
    const int m_l = lane & 15;         // row/col index within 16x16 fragment
    const int k_l = (lane >> 4) << 3;  // 8 contiguous k per lane

    // staging identity: thread covers px = lane, quad-group qg = wave
    const int s_px = lane;
    const int s_qg = wave;             // 0..7; quads q = qg*9 + j

    for (int c0 = 0; c0 < C_; c0 += CC) {
        // ---- stage bf16 columns: cols[px][0..287], 9 quads (4 k) / thread ----
#pragma unroll
        for (int j = 0; j < 9; ++j) {
            const int q = s_qg * 9 + j;          // quad 0..71
            short4_t vs;
#pragma unroll
            for (int jj = 0; jj < 4; ++jj) {
                const int idx = (q * 4 + jj) - s_qg * 36;  // = j*4+jj (static)
                const int c  = 4 * s_qg + idx / 9;          // idx/9 static
                const int kk = idx % 9;                     // static
                const uint32_t pidx = t_idx[kk * 64 + s_px];
                const f32x4    wv   = t_w[kk * 64 + s_px];
                const float* xb = x + ((size_t)(b * C_ + c0 + c) << 12);
                const int y0c =  pidx        & 255;
                const int x0c = (pidx >> 8)  & 255;
                const int y1c = (pidx >> 16) & 255;
                const int x1c = (pidx >> 24) & 255;
                const float v = wv[0] * xb[y0c * W_ + x0c]
                              + wv[1] * xb[y0c * W_ + x1c]
                              + wv[2] * xb[y1c * W_ + x0c]
                              + wv[3] * xb[y1c * W_ + x1c];
                vs[jj] = f2bf(v);
            }
            *reinterpret_cast<short4_t*>(&cols[s_px * PADK + q * 4]) = vs;
        }
        __syncthreads();

        // ---- MFMA over 9 k-steps ----
#pragma unroll
        for (int s = 0; s < 9; ++s) {
            const int krow = s * 32 + k_l;
            short8 bf[2];
#pragma unroll
            for (int nt = 0; nt < 2; ++nt)
                bf[nt] = *reinterpret_cast<const short8*>(
                    &cols[(px0 + nt * 16 + m_l) * PADK + krow]);
            const int kglob = c0 * 9 + krow;
#pragma unroll
            for (int mt = 0; mt < 4; ++mt) {
                const short8 af = *reinterpret_cast<const short8*>(
                    wbf + (size_t)(co0 + mt * 16 + m_l) * (C_ * KK_) + kglob);
#pragma unroll
                for (int nt = 0; nt < 2; ++nt)
                    acc[mt][nt] = __builtin_amdgcn_mfma_f32_16x16x32_bf16(
                        af, bf[nt], acc[mt][nt], 0, 0, 0);
            }
        }
        __syncthreads();
    }

    // ---- epilogue: D mapping col=lane&15 (n=px), row=(lane>>4)*4+r (m=co) ----
    const int r0 = (lane >> 4) << 2;
#pragma unroll
    for (int mt = 0; mt < 4; ++mt) {
#pragma unroll
        for (int r = 0; r < 4; ++r) {
            const int co = co0 + mt * 16 + r0 + r;
            const float bv = bias[co];
            float* orow = out + ((size_t)(b * CO_ + co) * H_ + ho) * W_;
#pragma unroll
            for (int nt = 0; nt < 2; ++nt) {
                const int wo = px0 + nt * 16 + m_l;
                orow[wo] = acc[mt][nt][r] + bv;
            }
        }
    }
}

extern "C" void kernel_launch(void* const* d_in, const int* in_sizes, int n_in,
                              void* d_out, int out_size, void* d_ws, size_t ws_size,
                              hipStream_t stream) {
    const float* x      = (const float*)d_in[0];
    const float* offset = (const float*)d_in[1];
    const float* weight = (const float*)d_in[2];
    const float* bias   = (const float*)d_in[3];
    float* out = (float*)d_out;
    short* wbf = (short*)d_ws;          // 589824 bf16 = 1.18 MB
    (void)in_sizes; (void)n_in; (void)out_size; (void)ws_size;

    const int n8 = (CO_ * C_ * KK_) / 8;        // 73728 short8 groups
    hipLaunchKernelGGL(w2bf, dim3((n8 + 255) / 256), dim3(256), 0, stream,
                       weight, wbf, n8);
    hipLaunchKernelGGL(dcn_mfma, dim3(64 * B_), dim3(512), 0, stream,
                       x, offset, wbf, bias, out);
}